// Round 15
// baseline (180.746 us; speedup 1.0000x reference)
//
#include <hip/hip_runtime.h>
#include <hip/hip_bf16.h>

#define NN 50000
#define NE 625000
#define DIM 128

#define NBKT 782     // ceil(50000/64) buckets of 64 src nodes
#define NBKTP 784    // padded to multiple of 4
#define CAP 1536     // per-bucket capacity (mean 800, sd ~28)
#define CHUNK 4096   // edges per bin block (153 bin blocks)
#define NCHUNK ((NE + CHUNK - 1) / CHUNK)  // 153

// mega_setup grid partition: bin FIRST (long blocks overlap xcast stream)
#define XCAST_NB 6250              // NN*DIM/4/256
#define PREP_NB 65                 // (DIM*DIM+DIM+255)/256
#define SETUP_NB (NCHUNK + XCAST_NB + PREP_NB)

using fragAB = __attribute__((ext_vector_type(8))) short;
using fragC  = __attribute__((ext_vector_type(4))) float;

__device__ __forceinline__ unsigned short f2bf(float f) {
    unsigned int u = __float_as_uint(f);
    unsigned int r = u + 0x7FFFu + ((u >> 16) & 1u);  // RNE
    return (unsigned short)(r >> 16);
}

__device__ __forceinline__ float bflo(unsigned v) { return __uint_as_float(v << 16); }
__device__ __forceinline__ float bfhi(unsigned v) { return __uint_as_float(v & 0xffff0000u); }

// ---------------- mega_setup: bin (blocks 0..152) | xcast | prep.
// bin needs bucket_cursor zeroed BEFORE launch (hipMemsetAsync).
// Record = (bucket:10 | src_local:6 | dst:16). myb<NBKTP guards REQUIRED.
__global__ __launch_bounds__(256) void mega_setup(
    const float* __restrict__ X, const int* __restrict__ ei,
    const float* __restrict__ L, const float* __restrict__ W,
    const float* __restrict__ mb, float* __restrict__ cb,
    unsigned short* __restrict__ Bh, unsigned short* __restrict__ Xbf,
    int* __restrict__ bucket_cursor, unsigned* __restrict__ staging) {
    __shared__ int cnt[NBKTP];
    __shared__ int base[NBKTP];
    __shared__ int gb[NBKTP];
    __shared__ int sarr[256];
    __shared__ unsigned staged[CHUNK];
    int blk = blockIdx.x;
    int t = threadIdx.x;

    if (blk >= NCHUNK) {
        int xb = blk - NCHUNK;
        if (xb < XCAST_NB) {
            // ---- xcast: X fp32 -> Xbf bf16 (compact NN x 128)
            int idx = (xb * 256 + t) * 4;
            float4 v = *(const float4*)(X + idx);
            uint2 p;
            p.x = (unsigned)f2bf(v.x) | ((unsigned)f2bf(v.y) << 16);
            p.y = (unsigned)f2bf(v.z) | ((unsigned)f2bf(v.w) << 16);
            *(uint2*)(Xbf + idx) = p;
        } else {
            // ---- prep: C = L@W, cb = L@msg_b, bf16 Bh = [L | C]
            int idx = (xb - XCAST_NB) * 256 + t;
            if (idx < DIM * DIM) {
                int o = idx >> 7, g = idx & 127;
                float s = 0.f;
                for (int f = 0; f < DIM; f++) s += L[o * DIM + f] * W[f * DIM + g];
                Bh[o * 256 + 128 + g] = f2bf(s);          // C part
                Bh[o * 256 + g] = f2bf(L[o * DIM + g]);   // L part
            } else if (idx < DIM * DIM + DIM) {
                int o = idx - DIM * DIM;
                float s = 0.f;
                for (int f = 0; f < DIM; f++) s += L[o * DIM + f] * mb[f];
                cb[o] = s;
            }
        }
        return;
    }

    // ---- bin @4096 (proven r6-r9/r14)
    int e0 = blk * CHUNK;
    int nthis = NE - e0; if (nthis > CHUNK) nthis = CHUNK;

    for (int i = t; i < NBKTP; i += 256) cnt[i] = 0;
    __syncthreads();

    unsigned pk[CHUNK / 256];
#pragma unroll
    for (int i = 0; i < CHUNK / 256; i++) {
        int e = e0 + i * 256 + t;
        if (e < NE) {
            int s = ei[e];
            int d = ei[NE + e];
            unsigned b = (unsigned)s >> 6;
            pk[i] = (b << 22) | ((unsigned)(s & 63) << 16) | (unsigned)d;
            atomicAdd(&cnt[b], 1);
        } else pk[i] = 0xFFFFFFFFu;
    }
    __syncthreads();

    int myb = t * 4;
    int s0 = 0;
    if (myb < NBKTP) s0 = cnt[myb] + cnt[myb + 1] + cnt[myb + 2] + cnt[myb + 3];
    sarr[t] = s0;
    __syncthreads();
    for (int off = 1; off < 256; off <<= 1) {
        int v = (t >= off) ? sarr[t - off] : 0;
        __syncthreads();
        sarr[t] += v;
        __syncthreads();
    }
    int run = sarr[t] - s0;  // exclusive prefix
    if (myb < NBKTP) {
        for (int i = 0; i < 4; i++) {
            int b = myb + i;
            base[b] = run;
            int c = cnt[b];
            gb[b] = (b < NBKT && c > 0) ? atomicAdd(&bucket_cursor[b], c) : 0;
            run += c;
        }
    }
    __syncthreads();
    if (myb < NBKTP) {
        for (int i = 0; i < 4; i++) cnt[myb + i] = base[myb + i];  // cursor
    }
    __syncthreads();

#pragma unroll
    for (int i = 0; i < CHUNK / 256; i++) {
        if (pk[i] != 0xFFFFFFFFu) {
            unsigned b = pk[i] >> 22;
            int pos = atomicAdd(&cnt[b], 1);
            staged[pos] = pk[i];
        }
    }
    __syncthreads();

    for (int idx = t; idx < nthis; idx += 256) {
        unsigned p = staged[idx];
        unsigned b = p >> 22;
        int pos = gb[b] + (idx - base[b]);
        if (pos >= 0 && pos < CAP) staging[(size_t)b * CAP + pos] = p;
    }
}

// ---------------- bucket_gather v2: sort + flattened record-stream gather.
// One wg (512 thr = 8 waves) per bucket. LDS counting-sort by src_local gives
// contiguous per-node runs; wave w owns nodes w*8..w*8+7 and streams its
// record range in batches of 8 (constant MLP-8), accumulating in registers
// and flushing one global write per node on run transitions (wave-uniform).
__global__ __launch_bounds__(512) void bucket_gather(
    const int* __restrict__ bucket_cursor, const unsigned* __restrict__ staging,
    const unsigned short* __restrict__ Xbf, unsigned short* __restrict__ Aggbf,
    int* __restrict__ deg) {
    __shared__ unsigned rec[CAP];
    __shared__ unsigned sorted_[CAP];
    __shared__ int hcnt[64];
    __shared__ int hbase[64];
    __shared__ int cur[64];
    int t = threadIdx.x;
    int b = blockIdx.x;
    int cnt_b = bucket_cursor[b];
    if (cnt_b > CAP) cnt_b = CAP;

    if (t < 64) hcnt[t] = 0;
    __syncthreads();
    for (int i = t; i < cnt_b; i += 512) {
        unsigned r = staging[(size_t)b * CAP + i];
        rec[i] = r;
        atomicAdd(&hcnt[(r >> 16) & 63], 1);
    }
    __syncthreads();
    if (t == 0) {
        int run = 0;
        for (int i = 0; i < 64; i++) { hbase[i] = run; run += hcnt[i]; }
    }
    __syncthreads();
    if (t < 64) {
        cur[t] = hbase[t];
        int src = b * 64 + t;
        if (src < NN) deg[src] = hcnt[t];
    }
    __syncthreads();
    for (int i = t; i < cnt_b; i += 512) {
        unsigned r = rec[i];
        int pos = atomicAdd(&cur[(r >> 16) & 63], 1);
        sorted_[pos] = r;
    }
    __syncthreads();

    // flattened gather: wave w streams records [hbase[w*8], end)
    int w = t >> 6, lane = t & 63;
    const unsigned* __restrict__ Xd = (const unsigned*)Xbf;  // 64 dwords/row
    unsigned* __restrict__ Ao = (unsigned*)Aggbf;            // 64 dwords/row
    int gs = hbase[w * 8];
    int ge = (w < 7) ? hbase[w * 8 + 8] : cnt_b;
    int cur_nl = -1;
    float ax = 0.f, ay = 0.f;
    for (int base2 = gs; base2 < ge; base2 += 8) {
        int nb = ge - base2; if (nb > 8) nb = 8;
        unsigned r[8];
        unsigned v[8];
#pragma unroll
        for (int i = 0; i < 8; i++) r[i] = (i < nb) ? sorted_[base2 + i] : 0u;
#pragma unroll
        for (int i = 0; i < 8; i++)
            if (i < nb) v[i] = Xd[(size_t)(r[i] & 0xFFFFu) * 64 + lane];
#pragma unroll
        for (int i = 0; i < 8; i++) {
            if (i < nb) {
                int nl = (r[i] >> 16) & 63;  // wave-uniform
                if (nl != cur_nl) {
                    if (cur_nl >= 0) {
                        unsigned pk = (unsigned)f2bf(ax) | ((unsigned)f2bf(ay) << 16);
                        Ao[(size_t)(b * 64 + cur_nl) * 64 + lane] = pk;
                    }
                    cur_nl = nl;
                    ax = 0.f; ay = 0.f;
                }
                ax += bflo(v[i]);
                ay += bfhi(v[i]);
            }
        }
    }
    if (cur_nl >= 0) {
        unsigned pk = (unsigned)f2bf(ax) | ((unsigned)f2bf(ay) << 16);
        Ao[(size_t)(b * 64 + cur_nl) * 64 + lane] = pk;
    }
    // zero-fill rows of deg-0 nodes in this wave's octet
#pragma unroll
    for (int ni = 0; ni < 8; ni++) {
        int local = w * 8 + ni;
        int node = b * 64 + local;
        if (node < NN && hcnt[local] == 0) Ao[(size_t)node * 64 + lane] = 0u;
    }
}

// ---------------- MFMA output GEMM (proven r5-r14):
// out[n][o] = relu( sum_k A[n][k]*Bhat[o][k] + deg[n]*cb[o] + lin_b[o] )
// A = [Xbf | Aggbf]; (1+eps) folded into k<128 B cols during staging.
__global__ __launch_bounds__(256) void outgemm_kernel(
    const unsigned short* __restrict__ Xbf, const unsigned short* __restrict__ Aggbf,
    const unsigned short* __restrict__ Bh, const int* __restrict__ deg,
    const float* __restrict__ cb, const float* __restrict__ lin_b,
    const float* __restrict__ epsp, float* __restrict__ out) {
    __shared__ unsigned short As[128 * 40];  // [row][32 k + 8 pad]
    __shared__ unsigned short Bs[128 * 40];
    int tid = threadIdx.x;
    int lane = tid & 63;
    int wave = tid >> 6;
    int m16 = lane & 15;
    int quad = lane >> 4;
    int waveM = (wave & 1) * 64;
    int waveN = (wave >> 1) * 64;
    int r0 = blockIdx.x * 128;
    float scale = 1.0f + *epsp;

    fragC acc[4][4];
#pragma unroll
    for (int i = 0; i < 4; i++)
#pragma unroll
        for (int j = 0; j < 4; j++) acc[i][j] = (fragC){0.f, 0.f, 0.f, 0.f};

    int srow = tid >> 1;
    int shalf = tid & 1;
    int arow = r0 + srow;
    if (arow >= NN) arow = NN - 1;

    for (int kc = 0; kc < 8; kc++) {
        int kb = kc * 32;
        {
            const unsigned short* asrc = (kc < 4) ? Xbf : Aggbf;
            int akb = kb & 127;
            const uint4* gp = (const uint4*)(asrc + (size_t)arow * 128 + akb + shalf * 16);
            uint4 w0 = gp[0];
            uint4 w1 = gp[1];
            uint4* lp = (uint4*)(As + srow * 40 + shalf * 16);
            lp[0] = w0;
            lp[1] = w1;
        }
        {
            const uint4* gp = (const uint4*)(Bh + (size_t)srow * 256 + kb + shalf * 16);
            uint4 w0 = gp[0];
            uint4 w1 = gp[1];
            if (kb < 128) {
                unsigned int* u0 = (unsigned int*)&w0;
                unsigned int* u1 = (unsigned int*)&w1;
#pragma unroll
                for (int q = 0; q < 4; q++) {
                    float lo = bflo(u0[q]) * scale;
                    float hi = bfhi(u0[q]) * scale;
                    u0[q] = (unsigned)f2bf(lo) | ((unsigned)f2bf(hi) << 16);
                    lo = bflo(u1[q]) * scale;
                    hi = bfhi(u1[q]) * scale;
                    u1[q] = (unsigned)f2bf(lo) | ((unsigned)f2bf(hi) << 16);
                }
            }
            uint4* lp = (uint4*)(Bs + srow * 40 + shalf * 16);
            lp[0] = w0;
            lp[1] = w1;
        }
        __syncthreads();

        fragAB a[4], bfr[4];
#pragma unroll
        for (int i = 0; i < 4; i++)
            a[i] = *(const fragAB*)(As + (waveM + i * 16 + m16) * 40 + quad * 8);
#pragma unroll
        for (int j = 0; j < 4; j++)
            bfr[j] = *(const fragAB*)(Bs + (waveN + j * 16 + m16) * 40 + quad * 8);
#pragma unroll
        for (int i = 0; i < 4; i++)
#pragma unroll
            for (int j = 0; j < 4; j++)
                acc[i][j] = __builtin_amdgcn_mfma_f32_16x16x32_bf16(a[i], bfr[j], acc[i][j], 0, 0, 0);
        __syncthreads();
    }

#pragma unroll
    for (int j = 0; j < 4; j++) {
        int col = waveN + j * 16 + m16;
        float cbc = cb[col];
        float lbc = lin_b[col];
#pragma unroll
        for (int i = 0; i < 4; i++) {
            int rbase = r0 + waveM + i * 16 + quad * 4;
#pragma unroll
            for (int r = 0; r < 4; r++) {
                int row = rbase + r;
                if (row < NN) {
                    float dg = (float)deg[row];
                    float v = acc[i][j][r] + dg * cbc + lbc;
                    out[(size_t)row * 128 + col] = fmaxf(v, 0.f);
                }
            }
        }
    }
}

extern "C" void kernel_launch(void* const* d_in, const int* in_sizes, int n_in,
                              void* d_out, int out_size, void* d_ws, size_t ws_size,
                              hipStream_t stream) {
    const float* X = (const float*)d_in[0];
    const int* ei = (const int*)d_in[1];
    const float* epsp = (const float*)d_in[2];
    const float* msg_w = (const float*)d_in[3];
    const float* msg_b = (const float*)d_in[4];
    const float* lin_w = (const float*)d_in[5];
    const float* lin_b = (const float*)d_in[6];
    float* out = (float*)d_out;

    // workspace (~31 MB)
    int* bucket_cursor = (int*)d_ws;                       // 800
    unsigned* staging = (unsigned*)(bucket_cursor + 800);  // NBKT*CAP = 4.8 MB
    int* deg = (int*)(staging + (size_t)NBKT * CAP);       // NN
    float* cb = (float*)(deg + NN);                        // DIM floats
    unsigned short* Bh = (unsigned short*)(cb + DIM);      // 128*256 bf16
    unsigned short* Xbf = Bh + 128 * 256;                  // NN*128 bf16 = 12.8 MB
    unsigned short* Aggbf = Xbf + (size_t)NN * 128;        // NN*128 bf16 = 12.8 MB

    hipMemsetAsync(bucket_cursor, 0, NBKTP * sizeof(int), stream);

    mega_setup<<<SETUP_NB, 256, 0, stream>>>(X, ei, lin_w, msg_w, msg_b, cb, Bh, Xbf,
                                             bucket_cursor, staging);
    bucket_gather<<<NBKT, 512, 0, stream>>>(bucket_cursor, staging, Xbf, Aggbf, deg);
    outgemm_kernel<<<(NN + 127) / 128, 256, 0, stream>>>(Xbf, Aggbf, Bh, deg, cb, lin_b,
                                                         epsp, out);
}

// Round 16
// 161.331 us; speedup vs baseline: 1.1203x; 1.1203x over previous
//
#include <hip/hip_runtime.h>
#include <hip/hip_bf16.h>

#define NN 50000
#define NE 625000
#define DIM 128

#define NBKT 782     // ceil(50000/64) buckets of 64 src nodes
#define NBKTP 784    // padded to multiple of 4
#define CAP 1536     // per-bucket capacity (mean 800, sd ~28)
#define CHUNK 4096   // edges per bin block (153 bin blocks)
#define NCHUNK ((NE + CHUNK - 1) / CHUNK)  // 153

// mega_setup grid partition: bin FIRST (long blocks overlap xcast stream)
#define XCAST_NB 6250              // NN*DIM/4/256
#define PREP_NB 65                 // (DIM*DIM+DIM+255)/256
#define SETUP_NB (NCHUNK + XCAST_NB + PREP_NB)

using fragAB = __attribute__((ext_vector_type(8))) short;
using fragC  = __attribute__((ext_vector_type(4))) float;

__device__ __forceinline__ unsigned short f2bf(float f) {
    unsigned int u = __float_as_uint(f);
    unsigned int r = u + 0x7FFFu + ((u >> 16) & 1u);  // RNE
    return (unsigned short)(r >> 16);
}

__device__ __forceinline__ float bflo(unsigned v) { return __uint_as_float(v << 16); }
__device__ __forceinline__ float bfhi(unsigned v) { return __uint_as_float(v & 0xffff0000u); }

// ---------------- mega_setup: bin (blocks 0..152, FIRST) | xcast | prep.
// bucket_cursor zeroed before launch (hipMemsetAsync).
// Record = (bucket:10 | src_local:6 | dst:16). myb<NBKTP guards REQUIRED.
__global__ __launch_bounds__(256) void mega_setup(
    const float* __restrict__ X, const int* __restrict__ ei,
    const float* __restrict__ L, const float* __restrict__ W,
    const float* __restrict__ mb, float* __restrict__ cb,
    unsigned short* __restrict__ Bh, unsigned short* __restrict__ Xbf,
    int* __restrict__ bucket_cursor, unsigned* __restrict__ staging) {
    __shared__ int cnt[NBKTP];
    __shared__ int base[NBKTP];
    __shared__ int gb[NBKTP];
    __shared__ int sarr[256];
    __shared__ unsigned staged[CHUNK];
    int blk = blockIdx.x;
    int t = threadIdx.x;

    if (blk >= NCHUNK) {
        int xb = blk - NCHUNK;
        if (xb < XCAST_NB) {
            // ---- xcast: X fp32 -> Xbf bf16 (compact NN x 128)
            int idx = (xb * 256 + t) * 4;
            float4 v = *(const float4*)(X + idx);
            uint2 p;
            p.x = (unsigned)f2bf(v.x) | ((unsigned)f2bf(v.y) << 16);
            p.y = (unsigned)f2bf(v.z) | ((unsigned)f2bf(v.w) << 16);
            *(uint2*)(Xbf + idx) = p;
        } else {
            // ---- prep: C = L@W, cb = L@msg_b, bf16 Bh = [L | C]
            int idx = (xb - XCAST_NB) * 256 + t;
            if (idx < DIM * DIM) {
                int o = idx >> 7, g = idx & 127;
                float s = 0.f;
                for (int f = 0; f < DIM; f++) s += L[o * DIM + f] * W[f * DIM + g];
                Bh[o * 256 + 128 + g] = f2bf(s);          // C part
                Bh[o * 256 + g] = f2bf(L[o * DIM + g]);   // L part
            } else if (idx < DIM * DIM + DIM) {
                int o = idx - DIM * DIM;
                float s = 0.f;
                for (int f = 0; f < DIM; f++) s += L[o * DIM + f] * mb[f];
                cb[o] = s;
            }
        }
        return;
    }

    // ---- bin @4096 (proven r6-r9/r14)
    int e0 = blk * CHUNK;
    int nthis = NE - e0; if (nthis > CHUNK) nthis = CHUNK;

    for (int i = t; i < NBKTP; i += 256) cnt[i] = 0;
    __syncthreads();

    unsigned pk[CHUNK / 256];
#pragma unroll
    for (int i = 0; i < CHUNK / 256; i++) {
        int e = e0 + i * 256 + t;
        if (e < NE) {
            int s = ei[e];
            int d = ei[NE + e];
            unsigned b = (unsigned)s >> 6;
            pk[i] = (b << 22) | ((unsigned)(s & 63) << 16) | (unsigned)d;
            atomicAdd(&cnt[b], 1);
        } else pk[i] = 0xFFFFFFFFu;
    }
    __syncthreads();

    int myb = t * 4;
    int s0 = 0;
    if (myb < NBKTP) s0 = cnt[myb] + cnt[myb + 1] + cnt[myb + 2] + cnt[myb + 3];
    sarr[t] = s0;
    __syncthreads();
    for (int off = 1; off < 256; off <<= 1) {
        int v = (t >= off) ? sarr[t - off] : 0;
        __syncthreads();
        sarr[t] += v;
        __syncthreads();
    }
    int run = sarr[t] - s0;  // exclusive prefix
    if (myb < NBKTP) {
        for (int i = 0; i < 4; i++) {
            int b = myb + i;
            base[b] = run;
            int c = cnt[b];
            gb[b] = (b < NBKT && c > 0) ? atomicAdd(&bucket_cursor[b], c) : 0;
            run += c;
        }
    }
    __syncthreads();
    if (myb < NBKTP) {
        for (int i = 0; i < 4; i++) cnt[myb + i] = base[myb + i];  // cursor
    }
    __syncthreads();

#pragma unroll
    for (int i = 0; i < CHUNK / 256; i++) {
        if (pk[i] != 0xFFFFFFFFu) {
            unsigned b = pk[i] >> 22;
            int pos = atomicAdd(&cnt[b], 1);
            staged[pos] = pk[i];
        }
    }
    __syncthreads();

    for (int idx = t; idx < nthis; idx += 256) {
        unsigned p = staged[idx];
        unsigned b = p >> 22;
        int pos = gb[b] + (idx - base[b]);
        if (pos >= 0 && pos < CAP) staging[(size_t)b * CAP + pos] = p;
    }
}

// ---------------- bucket_gather (r14-proven form): sort + per-node pairwise
// gather. One wg (512 thr = 8 waves) per bucket: LDS counting-sort by
// src_local, then each wave gathers 8 nodes; two 32-lane halves read
// different rows via uint2 (16 rows in flight in the MLP-8 loop).
__global__ __launch_bounds__(512) void bucket_gather(
    const int* __restrict__ bucket_cursor, const unsigned* __restrict__ staging,
    const unsigned short* __restrict__ Xbf, unsigned short* __restrict__ Aggbf,
    int* __restrict__ deg) {
    __shared__ unsigned rec[CAP];
    __shared__ unsigned sorted_[CAP];
    __shared__ int hcnt[64];
    __shared__ int hbase[64];
    __shared__ int cur[64];
    int t = threadIdx.x;
    int b = blockIdx.x;
    int cnt_b = bucket_cursor[b];
    if (cnt_b > CAP) cnt_b = CAP;

    if (t < 64) hcnt[t] = 0;
    __syncthreads();
    for (int i = t; i < cnt_b; i += 512) {
        unsigned r = staging[(size_t)b * CAP + i];
        rec[i] = r;
        atomicAdd(&hcnt[(r >> 16) & 63], 1);
    }
    __syncthreads();
    if (t == 0) {
        int run = 0;
        for (int i = 0; i < 64; i++) { hbase[i] = run; run += hcnt[i]; }
    }
    __syncthreads();
    if (t < 64) {
        cur[t] = hbase[t];
        int src = b * 64 + t;
        if (src < NN) deg[src] = hcnt[t];
    }
    __syncthreads();
    for (int i = t; i < cnt_b; i += 512) {
        unsigned r = rec[i];
        int pos = atomicAdd(&cur[(r >> 16) & 63], 1);
        sorted_[pos] = r;
    }
    __syncthreads();

    // gather phase: wave w -> nodes b*64 + w*8 .. +7
    int wave = t >> 6, lane = t & 63;
    int l32 = lane & 31, half = lane >> 5;
    const uint2* __restrict__ X2 = (const uint2*)Xbf;  // 32 uint2 per row
    for (int ni = 0; ni < 8; ni++) {
        int local = wave * 8 + ni;
        int node = b * 64 + local;
        if (node >= NN) continue;
        int start = hbase[local];  // same-addr LDS read -> broadcast
        int cnt = hcnt[local];
        float a0 = 0.f, a1 = 0.f, a2 = 0.f, a3 = 0.f;
        int pairs = cnt >> 1;
        int j = 0;
        for (; j + 8 <= pairs; j += 8) {
            int d[8];
#pragma unroll
            for (int i = 0; i < 8; i++)
                d[i] = (int)(sorted_[start + 2 * (j + i) + half] & 0xFFFFu);
            uint2 v[8];
#pragma unroll
            for (int i = 0; i < 8; i++) v[i] = X2[(size_t)d[i] * 32 + l32];
#pragma unroll
            for (int i = 0; i < 8; i++) {
                a0 += bflo(v[i].x);
                a1 += bfhi(v[i].x);
                a2 += bflo(v[i].y);
                a3 += bfhi(v[i].y);
            }
        }
        for (; j < pairs; j++) {
            int d = (int)(sorted_[start + 2 * j + half] & 0xFFFFu);
            uint2 v = X2[(size_t)d * 32 + l32];
            a0 += bflo(v.x);
            a1 += bfhi(v.x);
            a2 += bflo(v.y);
            a3 += bfhi(v.y);
        }
        if ((cnt & 1) && half == 0) {
            int d = (int)(sorted_[start + cnt - 1] & 0xFFFFu);
            uint2 v = X2[(size_t)d * 32 + l32];
            a0 += bflo(v.x);
            a1 += bfhi(v.x);
            a2 += bflo(v.y);
            a3 += bfhi(v.y);
        }
        a0 += __shfl_xor(a0, 32);
        a1 += __shfl_xor(a1, 32);
        a2 += __shfl_xor(a2, 32);
        a3 += __shfl_xor(a3, 32);
        if (half == 0) {
            uint2 p;
            p.x = (unsigned)f2bf(a0) | ((unsigned)f2bf(a1) << 16);
            p.y = (unsigned)f2bf(a2) | ((unsigned)f2bf(a3) << 16);
            ((uint2*)Aggbf)[(size_t)node * 32 + l32] = p;
        }
    }
}

// ---------------- MFMA output GEMM (proven r5-r15):
// out[n][o] = relu( sum_k A[n][k]*Bhat[o][k] + deg[n]*cb[o] + lin_b[o] )
// A = [Xbf | Aggbf]; (1+eps) folded into k<128 B cols during staging.
__global__ __launch_bounds__(256) void outgemm_kernel(
    const unsigned short* __restrict__ Xbf, const unsigned short* __restrict__ Aggbf,
    const unsigned short* __restrict__ Bh, const int* __restrict__ deg,
    const float* __restrict__ cb, const float* __restrict__ lin_b,
    const float* __restrict__ epsp, float* __restrict__ out) {
    __shared__ unsigned short As[128 * 40];  // [row][32 k + 8 pad]
    __shared__ unsigned short Bs[128 * 40];
    int tid = threadIdx.x;
    int lane = tid & 63;
    int wave = tid >> 6;
    int m16 = lane & 15;
    int quad = lane >> 4;
    int waveM = (wave & 1) * 64;
    int waveN = (wave >> 1) * 64;
    int r0 = blockIdx.x * 128;
    float scale = 1.0f + *epsp;

    fragC acc[4][4];
#pragma unroll
    for (int i = 0; i < 4; i++)
#pragma unroll
        for (int j = 0; j < 4; j++) acc[i][j] = (fragC){0.f, 0.f, 0.f, 0.f};

    int srow = tid >> 1;
    int shalf = tid & 1;
    int arow = r0 + srow;
    if (arow >= NN) arow = NN - 1;

    for (int kc = 0; kc < 8; kc++) {
        int kb = kc * 32;
        {
            const unsigned short* asrc = (kc < 4) ? Xbf : Aggbf;
            int akb = kb & 127;
            const uint4* gp = (const uint4*)(asrc + (size_t)arow * 128 + akb + shalf * 16);
            uint4 w0 = gp[0];
            uint4 w1 = gp[1];
            uint4* lp = (uint4*)(As + srow * 40 + shalf * 16);
            lp[0] = w0;
            lp[1] = w1;
        }
        {
            const uint4* gp = (const uint4*)(Bh + (size_t)srow * 256 + kb + shalf * 16);
            uint4 w0 = gp[0];
            uint4 w1 = gp[1];
            if (kb < 128) {
                unsigned int* u0 = (unsigned int*)&w0;
                unsigned int* u1 = (unsigned int*)&w1;
#pragma unroll
                for (int q = 0; q < 4; q++) {
                    float lo = bflo(u0[q]) * scale;
                    float hi = bfhi(u0[q]) * scale;
                    u0[q] = (unsigned)f2bf(lo) | ((unsigned)f2bf(hi) << 16);
                    lo = bflo(u1[q]) * scale;
                    hi = bfhi(u1[q]) * scale;
                    u1[q] = (unsigned)f2bf(lo) | ((unsigned)f2bf(hi) << 16);
                }
            }
            uint4* lp = (uint4*)(Bs + srow * 40 + shalf * 16);
            lp[0] = w0;
            lp[1] = w1;
        }
        __syncthreads();

        fragAB a[4], bfr[4];
#pragma unroll
        for (int i = 0; i < 4; i++)
            a[i] = *(const fragAB*)(As + (waveM + i * 16 + m16) * 40 + quad * 8);
#pragma unroll
        for (int j = 0; j < 4; j++)
            bfr[j] = *(const fragAB*)(Bs + (waveN + j * 16 + m16) * 40 + quad * 8);
#pragma unroll
        for (int i = 0; i < 4; i++)
#pragma unroll
            for (int j = 0; j < 4; j++)
                acc[i][j] = __builtin_amdgcn_mfma_f32_16x16x32_bf16(a[i], bfr[j], acc[i][j], 0, 0, 0);
        __syncthreads();
    }

#pragma unroll
    for (int j = 0; j < 4; j++) {
        int col = waveN + j * 16 + m16;
        float cbc = cb[col];
        float lbc = lin_b[col];
#pragma unroll
        for (int i = 0; i < 4; i++) {
            int rbase = r0 + waveM + i * 16 + quad * 4;
#pragma unroll
            for (int r = 0; r < 4; r++) {
                int row = rbase + r;
                if (row < NN) {
                    float dg = (float)deg[row];
                    float v = acc[i][j][r] + dg * cbc + lbc;
                    out[(size_t)row * 128 + col] = fmaxf(v, 0.f);
                }
            }
        }
    }
}

extern "C" void kernel_launch(void* const* d_in, const int* in_sizes, int n_in,
                              void* d_out, int out_size, void* d_ws, size_t ws_size,
                              hipStream_t stream) {
    const float* X = (const float*)d_in[0];
    const int* ei = (const int*)d_in[1];
    const float* epsp = (const float*)d_in[2];
    const float* msg_w = (const float*)d_in[3];
    const float* msg_b = (const float*)d_in[4];
    const float* lin_w = (const float*)d_in[5];
    const float* lin_b = (const float*)d_in[6];
    float* out = (float*)d_out;

    // workspace (~31 MB)
    int* bucket_cursor = (int*)d_ws;                       // 800
    unsigned* staging = (unsigned*)(bucket_cursor + 800);  // NBKT*CAP = 4.8 MB
    int* deg = (int*)(staging + (size_t)NBKT * CAP);       // NN
    float* cb = (float*)(deg + NN);                        // DIM floats
    unsigned short* Bh = (unsigned short*)(cb + DIM);      // 128*256 bf16
    unsigned short* Xbf = Bh + 128 * 256;                  // NN*128 bf16 = 12.8 MB
    unsigned short* Aggbf = Xbf + (size_t)NN * 128;        // NN*128 bf16 = 12.8 MB

    hipMemsetAsync(bucket_cursor, 0, NBKTP * sizeof(int), stream);

    mega_setup<<<SETUP_NB, 256, 0, stream>>>(X, ei, lin_w, msg_w, msg_b, cb, Bh, Xbf,
                                             bucket_cursor, staging);
    bucket_gather<<<NBKT, 512, 0, stream>>>(bucket_cursor, staging, Xbf, Aggbf, deg);
    outgemm_kernel<<<(NN + 127) / 128, 256, 0, stream>>>(Xbf, Aggbf, Bh, deg, cb, lin_b,
                                                         epsp, out);
}

// Round 17
// 158.459 us; speedup vs baseline: 1.1406x; 1.0181x over previous
//
#include <hip/hip_runtime.h>
#include <hip/hip_bf16.h>

#define NN 50000
#define NE 625000
#define DIM 128

#define NBKT 782     // ceil(50000/64) buckets of 64 src nodes
#define NBKTP 784    // padded to multiple of 4
#define CAP 1536     // per-bucket capacity (mean 800, sd ~28)
#define CHUNK 4096   // edges per bin block (153 bin blocks)
#define NCHUNK ((NE + CHUNK - 1) / CHUNK)  // 153

// mega_setup grid partition: bin FIRST (long blocks overlap xcast stream)
#define XCAST_NB 6250              // NN*DIM/4/256
#define PREP_NB 65                 // (DIM*DIM+DIM+255)/256
#define SETUP_NB (NCHUNK + XCAST_NB + PREP_NB)

using fragAB = __attribute__((ext_vector_type(8))) short;
using fragC  = __attribute__((ext_vector_type(4))) float;

__device__ __forceinline__ unsigned short f2bf(float f) {
    unsigned int u = __float_as_uint(f);
    unsigned int r = u + 0x7FFFu + ((u >> 16) & 1u);  // RNE
    return (unsigned short)(r >> 16);
}

__device__ __forceinline__ float bflo(unsigned v) { return __uint_as_float(v << 16); }
__device__ __forceinline__ float bfhi(unsigned v) { return __uint_as_float(v & 0xffff0000u); }

// ---------------- mega_setup: bin (blocks 0..152, FIRST) | xcast | prep.
// bucket_cursor zeroed before launch (hipMemsetAsync).
// prep folds (1+eps) into Bh's L-half so outgemm staging is a pure copy.
// Record = (bucket:10 | src_local:6 | dst:16). myb<NBKTP guards REQUIRED.
__global__ __launch_bounds__(256) void mega_setup(
    const float* __restrict__ X, const int* __restrict__ ei,
    const float* __restrict__ L, const float* __restrict__ W,
    const float* __restrict__ mb, const float* __restrict__ epsp,
    float* __restrict__ cb, unsigned short* __restrict__ Bh,
    unsigned short* __restrict__ Xbf,
    int* __restrict__ bucket_cursor, unsigned* __restrict__ staging) {
    __shared__ int cnt[NBKTP];
    __shared__ int base[NBKTP];
    __shared__ int gb[NBKTP];
    __shared__ int wsum[4];
    __shared__ unsigned staged[CHUNK];
    int blk = blockIdx.x;
    int t = threadIdx.x;

    if (blk >= NCHUNK) {
        int xb = blk - NCHUNK;
        if (xb < XCAST_NB) {
            // ---- xcast: X fp32 -> Xbf bf16 (compact NN x 128)
            int idx = (xb * 256 + t) * 4;
            float4 v = *(const float4*)(X + idx);
            uint2 p;
            p.x = (unsigned)f2bf(v.x) | ((unsigned)f2bf(v.y) << 16);
            p.y = (unsigned)f2bf(v.z) | ((unsigned)f2bf(v.w) << 16);
            *(uint2*)(Xbf + idx) = p;
        } else {
            // ---- prep: C = L@W, cb = L@msg_b, bf16 Bh = [(1+eps)L | C]
            int idx = (xb - XCAST_NB) * 256 + t;
            float scale = 1.0f + *epsp;
            if (idx < DIM * DIM) {
                int o = idx >> 7, g = idx & 127;
                float s = 0.f;
                for (int f = 0; f < DIM; f++) s += L[o * DIM + f] * W[f * DIM + g];
                Bh[o * 256 + 128 + g] = f2bf(s);                  // C part
                Bh[o * 256 + g] = f2bf(L[o * DIM + g] * scale);   // scaled L part
            } else if (idx < DIM * DIM + DIM) {
                int o = idx - DIM * DIM;
                float s = 0.f;
                for (int f = 0; f < DIM; f++) s += L[o * DIM + f] * mb[f];
                cb[o] = s;
            }
        }
        return;
    }

    // ---- bin @4096 (r6-r16 logic, scan via wave shuffles: 1 barrier not 16)
    int e0 = blk * CHUNK;
    int nthis = NE - e0; if (nthis > CHUNK) nthis = CHUNK;

    for (int i = t; i < NBKTP; i += 256) cnt[i] = 0;
    __syncthreads();

    unsigned pk[CHUNK / 256];
#pragma unroll
    for (int i = 0; i < CHUNK / 256; i++) {
        int e = e0 + i * 256 + t;
        if (e < NE) {
            int s = ei[e];
            int d = ei[NE + e];
            unsigned b = (unsigned)s >> 6;
            pk[i] = (b << 22) | ((unsigned)(s & 63) << 16) | (unsigned)d;
            atomicAdd(&cnt[b], 1);
        } else pk[i] = 0xFFFFFFFFu;
    }
    __syncthreads();

    int myb = t * 4;
    int s0 = 0;
    if (myb < NBKTP) s0 = cnt[myb] + cnt[myb + 1] + cnt[myb + 2] + cnt[myb + 3];
    // wave-level inclusive scan of s0 (64 lanes), then cross-wave combine
    int lane = t & 63, w = t >> 6;
    int v = s0;
#pragma unroll
    for (int off = 1; off < 64; off <<= 1) {
        int u = __shfl_up(v, off);
        if (lane >= off) v += u;
    }
    if (lane == 63) wsum[w] = v;
    __syncthreads();
    int add = 0;
#pragma unroll
    for (int i = 0; i < 4; i++)
        if (i < w) add += wsum[i];
    int run = v + add - s0;  // exclusive prefix for this thread's 4 counters
    if (myb < NBKTP) {
        for (int i = 0; i < 4; i++) {
            int b = myb + i;
            base[b] = run;
            int c = cnt[b];
            gb[b] = (b < NBKT && c > 0) ? atomicAdd(&bucket_cursor[b], c) : 0;
            run += c;
        }
    }
    __syncthreads();
    if (myb < NBKTP) {
        for (int i = 0; i < 4; i++) cnt[myb + i] = base[myb + i];  // cursor
    }
    __syncthreads();

#pragma unroll
    for (int i = 0; i < CHUNK / 256; i++) {
        if (pk[i] != 0xFFFFFFFFu) {
            unsigned b = pk[i] >> 22;
            int pos = atomicAdd(&cnt[b], 1);
            staged[pos] = pk[i];
        }
    }
    __syncthreads();

    for (int idx = t; idx < nthis; idx += 256) {
        unsigned p = staged[idx];
        unsigned b = p >> 22;
        int pos = gb[b] + (idx - base[b]);
        if (pos >= 0 && pos < CAP) staging[(size_t)b * CAP + pos] = p;
    }
}

// ---------------- bucket_gather (r14/r16-proven gather; hbase via wave scan).
// One wg (512 thr = 8 waves) per bucket: LDS counting-sort by src_local,
// then each wave gathers 8 nodes; two 32-lane halves read different rows
// via uint2 (16 rows in flight in the MLP-8 loop).
__global__ __launch_bounds__(512) void bucket_gather(
    const int* __restrict__ bucket_cursor, const unsigned* __restrict__ staging,
    const unsigned short* __restrict__ Xbf, unsigned short* __restrict__ Aggbf,
    int* __restrict__ deg) {
    __shared__ unsigned rec[CAP];
    __shared__ unsigned sorted_[CAP];
    __shared__ int hcnt[64];
    __shared__ int hbase[64];
    __shared__ int cur[64];
    int t = threadIdx.x;
    int b = blockIdx.x;
    int cnt_b = bucket_cursor[b];
    if (cnt_b > CAP) cnt_b = CAP;

    if (t < 64) hcnt[t] = 0;
    __syncthreads();
    for (int i = t; i < cnt_b; i += 512) {
        unsigned r = staging[(size_t)b * CAP + i];
        rec[i] = r;
        atomicAdd(&hcnt[(r >> 16) & 63], 1);
    }
    __syncthreads();
    if (t < 64) {  // wave 0: 64-lane shuffle scan replaces t==0 serial loop
        int c = hcnt[t];
        int v = c;
#pragma unroll
        for (int off = 1; off < 64; off <<= 1) {
            int u = __shfl_up(v, off);
            if (t >= off) v += u;
        }
        int ex = v - c;
        hbase[t] = ex;
        cur[t] = ex;
        int src = b * 64 + t;
        if (src < NN) deg[src] = c;
    }
    __syncthreads();
    for (int i = t; i < cnt_b; i += 512) {
        unsigned r = rec[i];
        int pos = atomicAdd(&cur[(r >> 16) & 63], 1);
        sorted_[pos] = r;
    }
    __syncthreads();

    // gather phase: wave w -> nodes b*64 + w*8 .. +7
    int wave = t >> 6, lane = t & 63;
    int l32 = lane & 31, half = lane >> 5;
    const uint2* __restrict__ X2 = (const uint2*)Xbf;  // 32 uint2 per row
    for (int ni = 0; ni < 8; ni++) {
        int local = wave * 8 + ni;
        int node = b * 64 + local;
        if (node >= NN) continue;
        int start = hbase[local];  // same-addr LDS read -> broadcast
        int cnt = hcnt[local];
        float a0 = 0.f, a1 = 0.f, a2 = 0.f, a3 = 0.f;
        int pairs = cnt >> 1;
        int j = 0;
        for (; j + 8 <= pairs; j += 8) {
            int d[8];
#pragma unroll
            for (int i = 0; i < 8; i++)
                d[i] = (int)(sorted_[start + 2 * (j + i) + half] & 0xFFFFu);
            uint2 v[8];
#pragma unroll
            for (int i = 0; i < 8; i++) v[i] = X2[(size_t)d[i] * 32 + l32];
#pragma unroll
            for (int i = 0; i < 8; i++) {
                a0 += bflo(v[i].x);
                a1 += bfhi(v[i].x);
                a2 += bflo(v[i].y);
                a3 += bfhi(v[i].y);
            }
        }
        for (; j < pairs; j++) {
            int d = (int)(sorted_[start + 2 * j + half] & 0xFFFFu);
            uint2 v = X2[(size_t)d * 32 + l32];
            a0 += bflo(v.x);
            a1 += bfhi(v.x);
            a2 += bflo(v.y);
            a3 += bfhi(v.y);
        }
        if ((cnt & 1) && half == 0) {
            int d = (int)(sorted_[start + cnt - 1] & 0xFFFFu);
            uint2 v = X2[(size_t)d * 32 + l32];
            a0 += bflo(v.x);
            a1 += bfhi(v.x);
            a2 += bflo(v.y);
            a3 += bfhi(v.y);
        }
        a0 += __shfl_xor(a0, 32);
        a1 += __shfl_xor(a1, 32);
        a2 += __shfl_xor(a2, 32);
        a3 += __shfl_xor(a3, 32);
        if (half == 0) {
            uint2 p;
            p.x = (unsigned)f2bf(a0) | ((unsigned)f2bf(a1) << 16);
            p.y = (unsigned)f2bf(a2) | ((unsigned)f2bf(a3) << 16);
            ((uint2*)Aggbf)[(size_t)node * 32 + l32] = p;
        }
    }
}

// ---------------- MFMA output GEMM:
// out[n][o] = relu( sum_k A[n][k]*Bhat[o][k] + deg[n]*cb[o] + lin_b[o] )
// A = [Xbf | Aggbf]; Bhat pre-scaled in prep -> staging is a pure copy.
__global__ __launch_bounds__(256) void outgemm_kernel(
    const unsigned short* __restrict__ Xbf, const unsigned short* __restrict__ Aggbf,
    const unsigned short* __restrict__ Bh, const int* __restrict__ deg,
    const float* __restrict__ cb, const float* __restrict__ lin_b,
    float* __restrict__ out) {
    __shared__ unsigned short As[128 * 40];  // [row][32 k + 8 pad]
    __shared__ unsigned short Bs[128 * 40];
    int tid = threadIdx.x;
    int lane = tid & 63;
    int wave = tid >> 6;
    int m16 = lane & 15;
    int quad = lane >> 4;
    int waveM = (wave & 1) * 64;
    int waveN = (wave >> 1) * 64;
    int r0 = blockIdx.x * 128;

    fragC acc[4][4];
#pragma unroll
    for (int i = 0; i < 4; i++)
#pragma unroll
        for (int j = 0; j < 4; j++) acc[i][j] = (fragC){0.f, 0.f, 0.f, 0.f};

    int srow = tid >> 1;
    int shalf = tid & 1;
    int arow = r0 + srow;
    if (arow >= NN) arow = NN - 1;

    for (int kc = 0; kc < 8; kc++) {
        int kb = kc * 32;
        {
            const unsigned short* asrc = (kc < 4) ? Xbf : Aggbf;
            int akb = kb & 127;
            const uint4* gp = (const uint4*)(asrc + (size_t)arow * 128 + akb + shalf * 16);
            uint4 w0 = gp[0];
            uint4 w1 = gp[1];
            uint4* lp = (uint4*)(As + srow * 40 + shalf * 16);
            lp[0] = w0;
            lp[1] = w1;
        }
        {
            const uint4* gp = (const uint4*)(Bh + (size_t)srow * 256 + kb + shalf * 16);
            uint4 w0 = gp[0];
            uint4 w1 = gp[1];
            uint4* lp = (uint4*)(Bs + srow * 40 + shalf * 16);
            lp[0] = w0;
            lp[1] = w1;
        }
        __syncthreads();

        fragAB a[4], bfr[4];
#pragma unroll
        for (int i = 0; i < 4; i++)
            a[i] = *(const fragAB*)(As + (waveM + i * 16 + m16) * 40 + quad * 8);
#pragma unroll
        for (int j = 0; j < 4; j++)
            bfr[j] = *(const fragAB*)(Bs + (waveN + j * 16 + m16) * 40 + quad * 8);
#pragma unroll
        for (int i = 0; i < 4; i++)
#pragma unroll
            for (int j = 0; j < 4; j++)
                acc[i][j] = __builtin_amdgcn_mfma_f32_16x16x32_bf16(a[i], bfr[j], acc[i][j], 0, 0, 0);
        __syncthreads();
    }

#pragma unroll
    for (int j = 0; j < 4; j++) {
        int col = waveN + j * 16 + m16;
        float cbc = cb[col];
        float lbc = lin_b[col];
#pragma unroll
        for (int i = 0; i < 4; i++) {
            int rbase = r0 + waveM + i * 16 + quad * 4;
#pragma unroll
            for (int r = 0; r < 4; r++) {
                int row = rbase + r;
                if (row < NN) {
                    float dg = (float)deg[row];
                    float v = acc[i][j][r] + dg * cbc + lbc;
                    out[(size_t)row * 128 + col] = fmaxf(v, 0.f);
                }
            }
        }
    }
}

extern "C" void kernel_launch(void* const* d_in, const int* in_sizes, int n_in,
                              void* d_out, int out_size, void* d_ws, size_t ws_size,
                              hipStream_t stream) {
    const float* X = (const float*)d_in[0];
    const int* ei = (const int*)d_in[1];
    const float* epsp = (const float*)d_in[2];
    const float* msg_w = (const float*)d_in[3];
    const float* msg_b = (const float*)d_in[4];
    const float* lin_w = (const float*)d_in[5];
    const float* lin_b = (const float*)d_in[6];
    float* out = (float*)d_out;

    // workspace (~31 MB)
    int* bucket_cursor = (int*)d_ws;                       // 800
    unsigned* staging = (unsigned*)(bucket_cursor + 800);  // NBKT*CAP = 4.8 MB
    int* deg = (int*)(staging + (size_t)NBKT * CAP);       // NN
    float* cb = (float*)(deg + NN);                        // DIM floats
    unsigned short* Bh = (unsigned short*)(cb + DIM);      // 128*256 bf16
    unsigned short* Xbf = Bh + 128 * 256;                  // NN*128 bf16 = 12.8 MB
    unsigned short* Aggbf = Xbf + (size_t)NN * 128;        // NN*128 bf16 = 12.8 MB

    hipMemsetAsync(bucket_cursor, 0, NBKTP * sizeof(int), stream);

    mega_setup<<<SETUP_NB, 256, 0, stream>>>(X, ei, lin_w, msg_w, msg_b, epsp, cb, Bh, Xbf,
                                             bucket_cursor, staging);
    bucket_gather<<<NBKT, 512, 0, stream>>>(bucket_cursor, staging, Xbf, Aggbf, deg);
    outgemm_kernel<<<(NN + 127) / 128, 256, 0, stream>>>(Xbf, Aggbf, Bh, deg, cb, lin_b, out);
}